// Round 1
// baseline (383.497 us; speedup 1.0000x reference)
//
#include <hip/hip_runtime.h>
#include <hip/hip_bf16.h>

// RecurrentLSTMStack: T=256, B=2048, D=16, H=64, 3 layers.
// Persistent batch-partitioned kernel: 256 WGs x 8 rows, full T-loop per WG.
// Gates-on-M MFMA (16x16x32 f16), interleaved gate rows -> lane-local i,f,g,o.
// Input dtype auto-detected (bf16 vs fp32) by detect_k; output follows.

#define TT 256
#define BB 2048
#define DD 16
#define HH 64

typedef __attribute__((ext_vector_type(8))) _Float16 halfx8;
typedef __attribute__((ext_vector_type(8))) unsigned short ushortx8;
typedef __attribute__((ext_vector_type(4))) float floatx4;

#if __has_builtin(__builtin_amdgcn_exp2f)
#define EXP2F(x) __builtin_amdgcn_exp2f(x)
#else
#define EXP2F(x) exp2f(x)
#endif
#if __has_builtin(__builtin_amdgcn_rcpf)
#define RCPF(x) __builtin_amdgcn_rcpf(x)
#else
#define RCPF(x) (1.0f/(x))
#endif

__device__ __forceinline__ float sigm(float x) {
  return RCPF(1.0f + EXP2F(-1.4426950408889634f * x));
}
__device__ __forceinline__ float tanh_f(float x) {
  float xc = fminf(fmaxf(x, -16.0f), 16.0f);
  float t = EXP2F(2.8853900817779268f * xc);   // exp(2*xc)
  return 1.0f - 2.0f * RCPF(t + 1.0f);
}
// Raw barrier: completes our ds ops but does NOT drain vmcnt, so the x[t+1]
// prefetch global load stays outstanding across barriers.
__device__ __forceinline__ void block_sync() {
  asm volatile("s_waitcnt lgkmcnt(0)" ::: "memory");
  __builtin_amdgcn_s_barrier();
}

// Detect whether x is bf16 (flag=1) or fp32-underneath (flag=0).
// Raw halfwords read as bf16: N(0,1) data -> ~0 values with |v|>=4;
// fp32 mantissa halves -> ~half of even indices are huge/NaN.
__global__ void detect_k(const unsigned short* __restrict__ xr, int* __restrict__ flag) {
  int cnt = 0;
  for (int i = threadIdx.x; i < 4096; i += 64) {
    float v = __uint_as_float(((unsigned int)xr[i]) << 16);
    if (!(fabsf(v) < 4.0f)) cnt++;
  }
#pragma unroll
  for (int o = 32; o > 0; o >>= 1) cnt += __shfl_down(cnt, o, 64);
  if (threadIdx.x == 0) flag[0] = (cnt < 100) ? 1 : 0;
}

// One layer's GEMM + redistribution. a0 ends up holding i,f,g,o (regs 0..3)
// for this lane's (unit,row) assignment.
#define LAYER_MFMA(XBUF, STRIDE, NKT, WA, BS)                                    \
    floatx4 a0 = BS[0], a1 = BS[1];                                              \
    {                                                                            \
      const _Float16* row_ = (XBUF) + (p * 16 + c) * (STRIDE);                   \
      _Pragma("unroll")                                                          \
      for (int kt = 0; kt < (NKT); ++kt) {                                       \
        halfx8 bfr = *(const halfx8*)(row_ + kt * 32 + 8 * g);                   \
        a0 = __builtin_amdgcn_mfma_f32_16x16x32_f16(WA[0][kt], bfr, a0, 0, 0, 0);\
        a1 = __builtin_amdgcn_mfma_f32_16x16x32_f16(WA[1][kt], bfr, a1, 0, 0, 0);\
      }                                                                          \
      _Pragma("unroll")                                                          \
      for (int q = 0; q < 4; ++q) {                                              \
        float v_ = __shfl_xor(a1[q], 8, 64);                                     \
        if (c >= 8) a0[q] = v_;                                                  \
      }                                                                          \
    }

__launch_bounds__(512, 2)
__global__ void lstm3_k(const void* __restrict__ xg,
                        const void* W0i, const void* W0h, const void* B0i, const void* B0h,
                        const void* W1i, const void* W1h, const void* B1i, const void* B1h,
                        const void* W2i, const void* W2h, const void* B2i, const void* B2h,
                        void* __restrict__ outp, const int* __restrict__ flagp) {
  const int tid = threadIdx.x;
  const int w = tid >> 6;        // wave 0..7
  const int lane = tid & 63;
  const int c = lane & 15;       // MFMA col (= batch row for B/C), A row within M-tile
  const int g = lane >> 4;       // lane group
  const int rowbase = blockIdx.x * 8;
  const int isbf = flagp ? flagp[0] : 1;

  // LDS input panels, double-buffered by step parity.
  // X0: [2][16][104]  row = [x(16) | h0(64) | pad]   (stride 104: 16B-aligned rows, spread banks)
  // X1: [2][16][136]  row = [h0(64) | h1(64) | pad]
  // X2: [2][16][136]  row = [h1(64) | h2(64) | pad]
  __shared__ __align__(16) _Float16 SH[2 * 16 * 104 + 2 * 2 * 16 * 136];
  _Float16* X0 = SH;
  _Float16* X1 = SH + 2 * 16 * 104;
  _Float16* X2 = X1 + 2 * 16 * 136;

  auto ldf = [&](const void* b, long i) -> float {
    return isbf ? __bfloat162float(((const __hip_bfloat16*)b)[i]) : ((const float*)b)[i];
  };
  auto ld8 = [&](const void* b, long i) -> halfx8 {   // 8 consecutive elems -> f16
    halfx8 r;
    if (isbf) {
      ushortx8 raw = *(const ushortx8*)((const unsigned short*)b + i);
#pragma unroll
      for (int j = 0; j < 8; ++j)
        r[j] = (_Float16)__uint_as_float(((unsigned int)raw[j]) << 16);
    } else {
      const float* s = (const float*)b + i;
#pragma unroll
      for (int j = 0; j < 8; ++j) r[j] = (_Float16)s[j];
    }
    return r;
  };
  // A-frag (weights): interleaved gate row r_il = 4*unit + q  <->  orig row q*64 + unit.
  // Wcat layer row = [W_ih(K_ih) | W_hh(64) | zero-pad]; lane holds k = 32*kt + 8*g .. +7.
  auto fragA = [&](const void* Wi, const void* Wh, int Kih, int Mt, int kt) -> halfx8 {
    int ril = Mt * 16 + c;
    int u = ril >> 2, q = ril & 3;
    int orig = q * 64 + u;
    int k0 = kt * 32 + 8 * g;
    if (k0 < Kih) return ld8(Wi, (long)orig * Kih + k0);
    if (k0 < Kih + 64) return ld8(Wh, (long)orig * 64 + (k0 - Kih));
    halfx8 z = {};
    return z;
  };

  // ---- persistent weight fragments + combined biases (registers) ----
  halfx8 wA0[2][3], wA1[2][4], wA2[2][4];
  floatx4 bs0[2], bs1[2], bs2[2];
#pragma unroll
  for (int m = 0; m < 2; ++m) {
    const int Mt = 2 * w + m;
#pragma unroll
    for (int kt = 0; kt < 3; ++kt) wA0[m][kt] = fragA(W0i, W0h, 16, Mt, kt);
#pragma unroll
    for (int kt = 0; kt < 4; ++kt) wA1[m][kt] = fragA(W1i, W1h, 64, Mt, kt);
#pragma unroll
    for (int kt = 0; kt < 4; ++kt) wA2[m][kt] = fragA(W2i, W2h, 64, Mt, kt);
    const int ub = 4 * Mt + g;   // C-layout: reg q <-> gate row 16*Mt+4*g+q <-> unit ub, gate q
#pragma unroll
    for (int q = 0; q < 4; ++q) {
      bs0[m][q] = ldf(B0i, 64 * q + ub) + ldf(B0h, 64 * q + ub);
      bs1[m][q] = ldf(B1i, 64 * q + ub) + ldf(B1h, 64 * q + ub);
      bs2[m][q] = ldf(B2i, 64 * q + ub) + ldf(B2h, 64 * q + ub);
    }
  }

  // zero LDS (rows 8..15 and pad columns stay zero forever -> h(0)=0, clean MFMA pads)
  for (int i = tid; i < (int)(sizeof(SH) / sizeof(_Float16)); i += 512) SH[i] = (_Float16)0.0f;
  block_sync();
  // stage x[0] into X0 parity 0
  if (tid < 16) {
    int r = tid >> 1, hf = tid & 1;
    halfx8 v = ld8(xg, ((long)0 * BB + rowbase + r) * DD + hf * 8);
    *(halfx8*)&X0[(0 * 16 + r) * 104 + hf * 8] = v;
  }

  // elementwise assignment: each lane owns (unit u_el, batch row r_el); all 64 lanes used.
  const int r_el = c & 7;
  const int u_el = 8 * w + ((c < 8) ? g : (4 + g));
  float c0s = 0.f, c1s = 0.f, c2s = 0.f;

#pragma unroll 1
  for (int t = 0; t < TT; ++t) {
    const int p = t & 1, np = p ^ 1;
    // prefetch x[t+1] (stays in flight across barriers; consumed end of step)
    halfx8 xreg = {};
    const bool loader = (tid < 16) && (t + 1 < TT);
    const int lr = tid >> 1, lhf = tid & 1;
    if (loader) xreg = ld8(xg, ((long)(t + 1) * BB + rowbase + lr) * DD + lhf * 8);

    block_sync();  // B0: x_t and h0(t-1) panels ready

    {  // ---- layer 0: Xin = [x_t | h0] ----
      LAYER_MFMA(X0, 104, 3, wA0, bs0)
      float I = sigm(a0[0]), F = sigm(a0[1]), G = tanh_f(a0[2]), O = sigm(a0[3]);
      float cn = F * c0s + I * G; c0s = cn;
      float hn = O * tanh_f(cn);
      _Float16 hh = (_Float16)hn;
      X0[(np * 16 + r_el) * 104 + 16 + u_el] = hh;  // self, next step
      X1[(p * 16 + r_el) * 136 + u_el] = hh;        // feeds L1 THIS step
    }
    block_sync();  // B1

    {  // ---- layer 1: Xin = [h0_t | h1_{t-1}] ----
      LAYER_MFMA(X1, 136, 4, wA1, bs1)
      float I = sigm(a0[0]), F = sigm(a0[1]), G = tanh_f(a0[2]), O = sigm(a0[3]);
      float cn = F * c1s + I * G; c1s = cn;
      float hn = O * tanh_f(cn);
      _Float16 hh = (_Float16)hn;
      X1[(np * 16 + r_el) * 136 + 64 + u_el] = hh;  // self, next step
      X2[(p * 16 + r_el) * 136 + u_el] = hh;        // feeds L2 THIS step
    }
    block_sync();  // B2

    {  // ---- layer 2: Xin = [h1_t | h2_{t-1}] ----
      LAYER_MFMA(X2, 136, 4, wA2, bs2)
      float I = sigm(a0[0]), F = sigm(a0[1]), G = tanh_f(a0[2]), O = sigm(a0[3]);
      float cn = F * c2s + I * G; c2s = cn;
      float hn = O * tanh_f(cn);
      X2[(np * 16 + r_el) * 136 + 64 + u_el] = (_Float16)hn;  // self, next step
      size_t oi = ((size_t)t * BB + rowbase + r_el) * HH + u_el;
      if (isbf) ((__hip_bfloat16*)outp)[oi] = __float2bfloat16(hn);
      else      ((float*)outp)[oi] = hn;
    }
    // write prefetched x[t+1] into next-parity panel (read after next B0)
    if (loader) *(halfx8*)&X0[(np * 16 + lr) * 104 + lhf * 8] = xreg;
  }
}

extern "C" void kernel_launch(void* const* d_in, const int* in_sizes, int n_in,
                              void* d_out, int out_size, void* d_ws, size_t ws_size,
                              hipStream_t stream) {
  (void)in_sizes; (void)n_in; (void)out_size;
  int* flag = (ws_size >= sizeof(int)) ? (int*)d_ws : nullptr;
  if (flag) {
    detect_k<<<dim3(1), dim3(64), 0, stream>>>((const unsigned short*)d_in[0], flag);
  }
  lstm3_k<<<dim3(BB / 8), dim3(512), 0, stream>>>(
      d_in[0],
      d_in[1], d_in[2], d_in[3], d_in[4],
      d_in[5], d_in[6], d_in[7], d_in[8],
      d_in[9], d_in[10], d_in[11], d_in[12],
      d_out, flag);
}

// Round 2
// 310.759 us; speedup vs baseline: 1.2341x; 1.2341x over previous
//
#include <hip/hip_runtime.h>
#include <hip/hip_bf16.h>

// RecurrentLSTMStack: T=256, B=2048, D=16, H=64, 3 layers.
// Persistent batch-partitioned kernel: 256 WGs x 8 rows, full T-loop per WG.
// R2: layer-diagonal pipeline (1 barrier/superstep), duplicated-column B-reads
// (no pad rows, no shuffles, LDS broadcast), single combined panel [x|h0|h1|h2].

#define TT 256
#define BB 2048
#define DD 16
#define HH 64

#define SROW 216                 // panel row stride in halves (432 B = 27*16B, odd -> spread banks)
#define PANEL (8 * SROW)         // halves per parity panel

typedef __attribute__((ext_vector_type(8))) _Float16 halfx8;
typedef __attribute__((ext_vector_type(8))) unsigned short ushortx8;
typedef __attribute__((ext_vector_type(4))) float floatx4;

#if __has_builtin(__builtin_amdgcn_exp2f)
#define EXP2F(x) __builtin_amdgcn_exp2f(x)
#else
#define EXP2F(x) exp2f(x)
#endif
#if __has_builtin(__builtin_amdgcn_rcpf)
#define RCPF(x) __builtin_amdgcn_rcpf(x)
#else
#define RCPF(x) (1.0f/(x))
#endif

__device__ __forceinline__ float sigm(float x) {
  return RCPF(1.0f + EXP2F(-1.4426950408889634f * x));
}
__device__ __forceinline__ float tanh_f(float x) {
  float xc = fminf(fmaxf(x, -16.0f), 16.0f);
  float t = EXP2F(2.8853900817779268f * xc);   // exp(2*xc)
  return 1.0f - 2.0f * RCPF(t + 1.0f);
}
// Raw barrier: completes our ds ops but does NOT drain vmcnt, so the x[t+1]
// prefetch / output stores stay outstanding across barriers.
__device__ __forceinline__ void block_sync() {
  asm volatile("s_waitcnt lgkmcnt(0)" ::: "memory");
  __builtin_amdgcn_s_barrier();
}

// Detect whether x is bf16 (flag=1) or fp32-underneath (flag=0).
__global__ void detect_k(const unsigned short* __restrict__ xr, int* __restrict__ flag) {
  int cnt = 0;
  for (int i = threadIdx.x; i < 4096; i += 64) {
    float v = __uint_as_float(((unsigned int)xr[i]) << 16);
    if (!(fabsf(v) < 4.0f)) cnt++;
  }
#pragma unroll
  for (int o = 32; o > 0; o >>= 1) cnt += __shfl_down(cnt, o, 64);
  if (threadIdx.x == 0) flag[0] = (cnt < 100) ? 1 : 0;
}

// One layer's GEMM. B-frag read: lane (c,g) reads row (c&7) -> lanes c and c+8
// broadcast the same address; D-cols 8..15 duplicate cols 0..7 (used by msel=1).
#define LAYER_MFMA(KSTART, NKT, WA, BS)                                          \
    floatx4 a0 = BS[0], a1 = BS[1];                                              \
    {                                                                            \
      const _Float16* row_ = Pp + rd_row + (KSTART);                             \
      _Pragma("unroll")                                                          \
      for (int kt = 0; kt < (NKT); ++kt) {                                       \
        halfx8 bfr = *(const halfx8*)(row_ + kt * 32 + 8 * g);                   \
        a0 = __builtin_amdgcn_mfma_f32_16x16x32_f16(WA[0][kt], bfr, a0, 0, 0, 0);\
        a1 = __builtin_amdgcn_mfma_f32_16x16x32_f16(WA[1][kt], bfr, a1, 0, 0, 0);\
      }                                                                          \
    }

__launch_bounds__(512, 2)
__global__ void lstm3_k(const void* __restrict__ xg,
                        const void* W0i, const void* W0h, const void* B0i, const void* B0h,
                        const void* W1i, const void* W1h, const void* B1i, const void* B1h,
                        const void* W2i, const void* W2h, const void* B2i, const void* B2h,
                        void* __restrict__ outp, const int* __restrict__ flagp) {
  const int tid = threadIdx.x;
  const int w = tid >> 6;        // wave 0..7
  const int lane = tid & 63;
  const int c = lane & 15;       // MFMA col (batch row, duplicated 8..15)
  const int g = lane >> 4;       // lane group
  const int rowbase = blockIdx.x * 8;
  const int isbf = flagp ? flagp[0] : 1;

  // Combined panel, double-buffered by superstep parity.
  // Row r (8 rows): [x(0..15) | h0(16..79) | h1(80..143) | h2(144..207) | pad]
  __shared__ __align__(16) _Float16 SH[2 * PANEL];

  auto ldf = [&](const void* b, long i) -> float {
    return isbf ? __bfloat162float(((const __hip_bfloat16*)b)[i]) : ((const float*)b)[i];
  };
  auto ld8 = [&](const void* b, long i) -> halfx8 {   // 8 consecutive elems -> f16
    halfx8 r;
    if (isbf) {
      ushortx8 raw = *(const ushortx8*)((const unsigned short*)b + i);
#pragma unroll
      for (int j = 0; j < 8; ++j)
        r[j] = (_Float16)__uint_as_float(((unsigned int)raw[j]) << 16);
    } else {
      const float* s = (const float*)b + i;
#pragma unroll
      for (int j = 0; j < 8; ++j) r[j] = (_Float16)s[j];
    }
    return r;
  };
  // A-frag (weights): interleaved gate row r_il = 4*unit + q  <->  orig row q*64 + unit.
  auto fragA = [&](const void* Wi, const void* Wh, int Kih, int Mt, int kt) -> halfx8 {
    int ril = Mt * 16 + c;
    int u = ril >> 2, q = ril & 3;
    int orig = q * 64 + u;
    int k0 = kt * 32 + 8 * g;
    if (k0 < Kih) return ld8(Wi, (long)orig * Kih + k0);
    if (k0 < Kih + 64) return ld8(Wh, (long)orig * 64 + (k0 - Kih));
    halfx8 z = {};
    return z;
  };

  // ---- persistent weight fragments + combined biases (registers) ----
  halfx8 wA0[2][3], wA1[2][4], wA2[2][4];
  floatx4 bs0[2], bs1[2], bs2[2];
#pragma unroll
  for (int m = 0; m < 2; ++m) {
    const int Mt = 2 * w + m;
#pragma unroll
    for (int kt = 0; kt < 3; ++kt) wA0[m][kt] = fragA(W0i, W0h, 16, Mt, kt);
#pragma unroll
    for (int kt = 0; kt < 4; ++kt) wA1[m][kt] = fragA(W1i, W1h, 64, Mt, kt);
#pragma unroll
    for (int kt = 0; kt < 4; ++kt) wA2[m][kt] = fragA(W2i, W2h, 64, Mt, kt);
    const int ub = 4 * Mt + g;   // C-layout: reg q <-> gate row 16*Mt+4*g+q <-> unit ub, gate q
#pragma unroll
    for (int q = 0; q < 4; ++q) {
      bs0[m][q] = ldf(B0i, 64 * q + ub) + ldf(B0h, 64 * q + ub);
      bs1[m][q] = ldf(B1i, 64 * q + ub) + ldf(B1h, 64 * q + ub);
      bs2[m][q] = ldf(B2i, 64 * q + ub) + ldf(B2h, 64 * q + ub);
    }
  }

  // zero both panels (h(0)=0; pad cols stay zero forever)
  for (int i = tid; i < 2 * PANEL; i += 512) SH[i] = (_Float16)0.0f;
  block_sync();
  // stage x[0] into parity-0 panel
  if (tid < 16) {
    int r = tid >> 1, hf = tid & 1;
    *(halfx8*)&SH[r * SROW + hf * 8] = ld8(xg, ((long)0 * BB + rowbase + r) * DD + hf * 8);
  }

  // cell assignment: 1 cell/lane. Lane (c,g) of wave w owns unit 8w+4*msel+g, row c&7.
  const int msel = c >> 3;
  const int r_el = c & 7;
  const int u_el = 8 * w + 4 * msel + g;
  const int rd_row = (c & 7) * SROW;          // B-frag row (broadcast pairs)
  const int wr_base = r_el * SROW + u_el;     // + layer col offset + parity base
  float c0s = 0.f, c1s = 0.f, c2s = 0.f;

#pragma unroll 1
  for (int s = 0; s < TT + 2; ++s) {
    const int p = s & 1, np = p ^ 1;
    const _Float16* Pp = SH + p * PANEL;
    _Float16* Pn = SH + np * PANEL;

    // prefetch x[s+1] (global load stays in flight across the barrier)
    halfx8 xreg = {};
    const bool loader = (tid < 16) && (s + 1 < TT);
    if (loader)
      xreg = ld8(xg, ((long)(s + 1) * BB + rowbase + (tid >> 1)) * DD + (tid & 1) * 8);

    block_sync();  // panel[p] (written last superstep) now readable

    if (s < TT) {  // ---- L0: t=s, input cols [0..80) = [x|h0] ----
      LAYER_MFMA(0, 3, wA0, bs0)
      floatx4 gv = msel ? a1 : a0;
      float I = sigm(gv[0]), F = sigm(gv[1]), G = tanh_f(gv[2]), O = sigm(gv[3]);
      float cn = F * c0s + I * G; c0s = cn;
      Pn[wr_base + 16] = (_Float16)(O * tanh_f(cn));
    }
    if (s >= 1 && s <= TT) {  // ---- L1: t=s-1, input cols [16..144) = [h0|h1] ----
      LAYER_MFMA(16, 4, wA1, bs1)
      floatx4 gv = msel ? a1 : a0;
      float I = sigm(gv[0]), F = sigm(gv[1]), G = tanh_f(gv[2]), O = sigm(gv[3]);
      float cn = F * c1s + I * G; c1s = cn;
      Pn[wr_base + 80] = (_Float16)(O * tanh_f(cn));
    }
    if (s >= 2) {  // ---- L2: t=s-2, input cols [80..208) = [h1|h2] ----
      LAYER_MFMA(80, 4, wA2, bs2)
      floatx4 gv = msel ? a1 : a0;
      float I = sigm(gv[0]), F = sigm(gv[1]), G = tanh_f(gv[2]), O = sigm(gv[3]);
      float cn = F * c2s + I * G; c2s = cn;
      float hn = O * tanh_f(cn);
      Pn[wr_base + 144] = (_Float16)hn;
      size_t oi = ((size_t)(s - 2) * BB + rowbase + r_el) * HH + u_el;
      if (isbf) ((__hip_bfloat16*)outp)[oi] = __float2bfloat16(hn);
      else      ((float*)outp)[oi] = hn;
    }
    // write prefetched x[s+1] into next-parity panel (read at superstep s+1)
    if (loader)
      *(halfx8*)&Pn[(tid >> 1) * SROW + (tid & 1) * 8] = xreg;
  }
}

extern "C" void kernel_launch(void* const* d_in, const int* in_sizes, int n_in,
                              void* d_out, int out_size, void* d_ws, size_t ws_size,
                              hipStream_t stream) {
  (void)in_sizes; (void)n_in; (void)out_size;
  int* flag = (ws_size >= sizeof(int)) ? (int*)d_ws : nullptr;
  if (flag) {
    detect_k<<<dim3(1), dim3(64), 0, stream>>>((const unsigned short*)d_in[0], flag);
  }
  lstm3_k<<<dim3(BB / 8), dim3(512), 0, stream>>>(
      d_in[0],
      d_in[1], d_in[2], d_in[3], d_in[4],
      d_in[5], d_in[6], d_in[7], d_in[8],
      d_in[9], d_in[10], d_in[11], d_in[12],
      d_out, flag);
}

// Round 3
// 276.744 us; speedup vs baseline: 1.3857x; 1.1229x over previous
//
#include <hip/hip_runtime.h>
#include <hip/hip_bf16.h>

// RecurrentLSTMStack: T=256, B=2048, D=16, H=64, 3 layers.
// R3: compile-time double-buffer parity (unroll x2), panel [h0|h1|h2|x] with
// 32-aligned shared K-blocks (7 ds_read_b128/wave, reused across layers),
// branch-free MFMA+nonlin core with guarded writes only.

#define TT 256
#define BB 2048
#define DD 16
#define HH 64

#define SROW 216                 // halves/row: 108 words, 108%32=12 -> full-bank spread
#define PANEL (8 * SROW)         // 1728 halves per parity panel
#define H0O 0
#define H1O 64
#define H2O 128
#define XO  192

typedef __attribute__((ext_vector_type(8))) _Float16 halfx8;
typedef __attribute__((ext_vector_type(8))) unsigned short ushortx8;
typedef __attribute__((ext_vector_type(4))) float floatx4;

#if __has_builtin(__builtin_amdgcn_exp2f)
#define EXP2F(x) __builtin_amdgcn_exp2f(x)
#else
#define EXP2F(x) exp2f(x)
#endif
#if __has_builtin(__builtin_amdgcn_rcpf)
#define RCPF(x) __builtin_amdgcn_rcpf(x)
#else
#define RCPF(x) (1.0f/(x))
#endif

__device__ __forceinline__ float sigm(float x) {
  return RCPF(1.0f + EXP2F(-1.4426950408889634f * x));
}
// no clamp: exp2(+inf)=inf -> rcp(inf)=0 -> 1; exp2(-inf)=0 -> rcp(1)=1 -> -1
__device__ __forceinline__ float tanh_f(float x) {
  float t = EXP2F(2.8853900817779268f * x);
  return 1.0f - 2.0f * RCPF(t + 1.0f);
}
// Raw barrier: waits our ds ops, does NOT drain vmcnt (x prefetch stays in flight).
__device__ __forceinline__ void block_sync() {
  asm volatile("s_waitcnt lgkmcnt(0)" ::: "memory");
  __builtin_amdgcn_s_barrier();
}

__global__ void detect_k(const unsigned short* __restrict__ xr, int* __restrict__ flag) {
  int cnt = 0;
  for (int i = threadIdx.x; i < 4096; i += 64) {
    float v = __uint_as_float(((unsigned int)xr[i]) << 16);
    if (!(fabsf(v) < 4.0f)) cnt++;
  }
#pragma unroll
  for (int o = 32; o > 0; o >>= 1) cnt += __shfl_down(cnt, o, 64);
  if (threadIdx.x == 0) flag[0] = (cnt < 100) ? 1 : 0;
}

#define MF(A, B, C) __builtin_amdgcn_mfma_f32_16x16x32_f16(A, B, C, 0, 0, 0)

#define BODY(S_, PPB, PNB)                                                        \
  {                                                                               \
    const int s_ = (S_);                                                          \
    halfx8 xreg = {};                                                             \
    const bool loader = (tid < 16) && (s_ + 1 < TT);                              \
    if (loader)                                                                   \
      xreg = ld8(xg, ((long)(s_ + 1) * BB + rowbase + (tid >> 1)) * DD + (tid & 1) * 8); \
    block_sync();                                                                 \
    const _Float16* PpR = SH + (PPB) + rd_off;                                    \
    _Float16* Pn = SH + (PNB);                                                    \
    halfx8 r0 = *(const halfx8*)(PpR + 0);                                        \
    halfx8 r1 = *(const halfx8*)(PpR + 32);                                       \
    halfx8 r2 = *(const halfx8*)(PpR + 64);                                       \
    halfx8 r3 = *(const halfx8*)(PpR + 96);                                       \
    halfx8 r4 = *(const halfx8*)(PpR + 128);                                      \
    halfx8 r5 = *(const halfx8*)(PpR + 160);                                      \
    halfx8 r6 = *(const halfx8*)(PpR + 192);                                      \
    floatx4 a00 = bs0[0], a01 = bs0[1];                                           \
    floatx4 a10 = bs1[0], a11 = bs1[1];                                           \
    floatx4 a20 = bs2[0], a21 = bs2[1];                                           \
    a00 = MF(wA0[0][0], r0, a00); a01 = MF(wA0[1][0], r0, a01);                   \
    a10 = MF(wA1[0][0], r0, a10); a11 = MF(wA1[1][0], r0, a11);                   \
    a00 = MF(wA0[0][1], r1, a00); a01 = MF(wA0[1][1], r1, a01);                   \
    a10 = MF(wA1[0][1], r1, a10); a11 = MF(wA1[1][1], r1, a11);                   \
    a20 = MF(wA2[0][0], r2, a20); a21 = MF(wA2[1][0], r2, a21);                   \
    a10 = MF(wA1[0][2], r2, a10); a11 = MF(wA1[1][2], r2, a11);                   \
    a20 = MF(wA2[0][1], r3, a20); a21 = MF(wA2[1][1], r3, a21);                   \
    a10 = MF(wA1[0][3], r3, a10); a11 = MF(wA1[1][3], r3, a11);                   \
    a20 = MF(wA2[0][2], r4, a20); a21 = MF(wA2[1][2], r4, a21);                   \
    a20 = MF(wA2[0][3], r5, a20); a21 = MF(wA2[1][3], r5, a21);                   \
    a00 = MF(wA0[0][2], r6, a00); a01 = MF(wA0[1][2], r6, a01);                   \
    { floatx4 gv = msel ? a01 : a00;                                              \
      float I = sigm(gv[0]), F = sigm(gv[1]), G = tanh_f(gv[2]), O = sigm(gv[3]); \
      float cn = F * c0s + I * G;                                                 \
      float hn = O * tanh_f(cn);                                                  \
      if (s_ < TT) { c0s = cn; Pn[wr_base + H0O] = (_Float16)hn; } }              \
    { floatx4 gv = msel ? a11 : a10;                                              \
      float I = sigm(gv[0]), F = sigm(gv[1]), G = tanh_f(gv[2]), O = sigm(gv[3]); \
      float cn = F * c1s + I * G;                                                 \
      float hn = O * tanh_f(cn);                                                  \
      if (s_ >= 1 && s_ <= TT) { c1s = cn; Pn[wr_base + H1O] = (_Float16)hn; } }  \
    { floatx4 gv = msel ? a21 : a20;                                              \
      float I = sigm(gv[0]), F = sigm(gv[1]), G = tanh_f(gv[2]), O = sigm(gv[3]); \
      float cn = F * c2s + I * G;                                                 \
      float hn = O * tanh_f(cn);                                                  \
      if (s_ >= 2) { c2s = cn; Pn[wr_base + H2O] = (_Float16)hn;                  \
        long oi = (long)(s_ - 2) * ((long)BB * HH) + olane;                       \
        if (isbf) ((__hip_bfloat16*)outp)[oi] = __float2bfloat16(hn);             \
        else ((float*)outp)[oi] = hn; } }                                         \
    if (loader) *(halfx8*)&Pn[(tid >> 1) * SROW + XO + (tid & 1) * 8] = xreg;     \
  }

__launch_bounds__(512, 2)
__global__ void lstm3_k(const void* __restrict__ xg,
                        const void* W0i, const void* W0h, const void* B0i, const void* B0h,
                        const void* W1i, const void* W1h, const void* B1i, const void* B1h,
                        const void* W2i, const void* W2h, const void* B2i, const void* B2h,
                        void* __restrict__ outp, const int* __restrict__ flagp) {
  const int tid = threadIdx.x;
  const int w = tid >> 6;        // wave 0..7
  const int lane = tid & 63;
  const int c = lane & 15;       // MFMA col (batch row, duplicated 8..15)
  const int g = lane >> 4;       // k-slot group
  const int rowbase = blockIdx.x * 8;
  const int isbf = flagp ? flagp[0] : 1;

  // Panel row r: [h0(0..63) | h1(64..127) | h2(128..191) | x(192..207) | pad(208..215)]
  // +32 zeroed tail halves: L0's r6 read (g=3, row 7, parity 1) lands there.
  __shared__ __align__(16) _Float16 SH[2 * PANEL + 32];

  auto ldf = [&](const void* b, long i) -> float {
    return isbf ? __bfloat162float(((const __hip_bfloat16*)b)[i]) : ((const float*)b)[i];
  };
  auto ld8 = [&](const void* b, long i) -> halfx8 {
    halfx8 r;
    if (isbf) {
      ushortx8 raw = *(const ushortx8*)((const unsigned short*)b + i);
#pragma unroll
      for (int j = 0; j < 8; ++j)
        r[j] = (_Float16)__uint_as_float(((unsigned int)raw[j]) << 16);
    } else {
      const float* s = (const float*)b + i;
#pragma unroll
      for (int j = 0; j < 8; ++j) r[j] = (_Float16)s[j];
    }
    return r;
  };

  // ---- persistent weight fragments + combined biases ----
  // Interleaved gate row r_il = 4*unit + q <-> orig row q*64 + unit.
  // K-block order per layer: L0 {h0:0, h0:32, x:192}, L1 {h0,h0,h1,h1}, L2 {h1,h1,h2,h2}.
  halfx8 wA0[2][3], wA1[2][4], wA2[2][4];
  floatx4 bs0[2], bs1[2], bs2[2];
#pragma unroll
  for (int m = 0; m < 2; ++m) {
    const int Mt = 2 * w + m;
    const int ril = Mt * 16 + c;
    const int u = ril >> 2, q = ril & 3;
    const long orig = q * 64 + u;
    halfx8 z = {};
    wA0[m][0] = ld8(W0h, orig * 64 + 8 * g);
    wA0[m][1] = ld8(W0h, orig * 64 + 32 + 8 * g);
    wA0[m][2] = (g == 0) ? ld8(W0i, orig * 16)
              : (g == 1) ? ld8(W0i, orig * 16 + 8) : z;
    wA1[m][0] = ld8(W1i, orig * 64 + 8 * g);
    wA1[m][1] = ld8(W1i, orig * 64 + 32 + 8 * g);
    wA1[m][2] = ld8(W1h, orig * 64 + 8 * g);
    wA1[m][3] = ld8(W1h, orig * 64 + 32 + 8 * g);
    wA2[m][0] = ld8(W2i, orig * 64 + 8 * g);
    wA2[m][1] = ld8(W2i, orig * 64 + 32 + 8 * g);
    wA2[m][2] = ld8(W2h, orig * 64 + 8 * g);
    wA2[m][3] = ld8(W2h, orig * 64 + 32 + 8 * g);
    const int ub = 4 * Mt + g;
#pragma unroll
    for (int qq = 0; qq < 4; ++qq) {
      bs0[m][qq] = ldf(B0i, 64 * qq + ub) + ldf(B0h, 64 * qq + ub);
      bs1[m][qq] = ldf(B1i, 64 * qq + ub) + ldf(B1h, 64 * qq + ub);
      bs2[m][qq] = ldf(B2i, 64 * qq + ub) + ldf(B2h, 64 * qq + ub);
    }
  }

  for (int i = tid; i < 2 * PANEL + 32; i += 512) SH[i] = (_Float16)0.0f;
  block_sync();
  if (tid < 16) {  // stage x[0] into parity-0 panel
    *(halfx8*)&SH[(tid >> 1) * SROW + XO + (tid & 1) * 8] =
        ld8(xg, ((long)0 * BB + rowbase + (tid >> 1)) * DD + (tid & 1) * 8);
  }

  const int msel = c >> 3;
  const int r_el = c & 7;
  const int u_el = 8 * w + 4 * msel + g;
  const int rd_off = (c & 7) * SROW + 8 * g;
  const int wr_base = r_el * SROW + u_el;
  const long olane = ((long)rowbase + r_el) * HH + u_el;
  float c0s = 0.f, c1s = 0.f, c2s = 0.f;

#pragma unroll 1
  for (int s2 = 0; s2 < (TT + 2) / 2; ++s2) {
    const int s = 2 * s2;
    BODY(s, 0, PANEL)
    BODY(s + 1, PANEL, 0)
  }
}

extern "C" void kernel_launch(void* const* d_in, const int* in_sizes, int n_in,
                              void* d_out, int out_size, void* d_ws, size_t ws_size,
                              hipStream_t stream) {
  (void)in_sizes; (void)n_in; (void)out_size;
  int* flag = (ws_size >= sizeof(int)) ? (int*)d_ws : nullptr;
  if (flag) {
    detect_k<<<dim3(1), dim3(64), 0, stream>>>((const unsigned short*)d_in[0], flag);
  }
  lstm3_k<<<dim3(BB / 8), dim3(512), 0, stream>>>(
      d_in[0],
      d_in[1], d_in[2], d_in[3], d_in[4],
      d_in[5], d_in[6], d_in[7], d_in[8],
      d_in[9], d_in[10], d_in[11], d_in[12],
      d_out, flag);
}